// Round 1
// baseline (337.320 us; speedup 1.0000x reference)
//
#include <hip/hip_runtime.h>

#define VN 49152
#define DEG 20
#define NB 2
#define MROWS (NB * VN)   // 98304 rows

static constexpr float BN_EPS = 1e-5f;

typedef short bf16x8 __attribute__((ext_vector_type(8)));
typedef float floatx4 __attribute__((ext_vector_type(4)));

__device__ __forceinline__ unsigned short f2bf(float f) {
  unsigned int u = __builtin_bit_cast(unsigned int, f);
  u += 0x7FFFu + ((u >> 16) & 1u);            // RNE
  return (unsigned short)(u >> 16);
}
__device__ __forceinline__ float bf2f(unsigned short h) {
  unsigned int u = ((unsigned int)h) << 16;
  return __builtin_bit_cast(float, u);
}
// packed-bf16 tricks: 1 VALU per element
__device__ __forceinline__ float bflo(unsigned int u) {
  return __builtin_bit_cast(float, u << 16);
}
__device__ __forceinline__ float bfhi(unsigned int u) {
  return __builtin_bit_cast(float, u & 0xFFFF0000u);
}
__device__ __forceinline__ unsigned int packbf(float a, float b) {
  return (unsigned int)f2bf(a) | ((unsigned int)f2bf(b) << 16);
}

// Feature planes (64-ch) are stored SWIZZLED as 4 sub-planes
// [batch][chalf][VN][32]: addr(b,v,ch) = ((b*2 + ch/32)*VN + v)*32 + ch%32.
// A (batch,chalf) combo = contiguous 3.15 MB -> fits one XCD L2.
// spmm blocks pin combo via blockIdx%8 so each combo lives on 2 XCDs.
//
// BN stats: each GEMM accumulates per-channel sum/sumsq into global gsum via
// atomics; the LAST block (device atomic counter) computes sc/sh in-kernel.
// This removes the three single-block reduce dispatches from the critical path.
// h1 = relu(bn1(t1)) is never materialized: consumers apply the affine inline.

// ======================= GEMM1: t1 = x @ W1 + b1 ===========================
#define LDA1 136
__global__ __launch_bounds__(256) void gemm1(const float* __restrict__ X,
    const float* __restrict__ W, const float* __restrict__ bias,
    const float* __restrict__ gamma, const float* __restrict__ beta,
    unsigned short* __restrict__ Y, float* __restrict__ gsum,
    int* __restrict__ counter, float* __restrict__ scshOut) {
  __shared__ unsigned short As[128 * LDA1];
  __shared__ unsigned short Bs[64 * LDA1];
  __shared__ float sred[128];
  __shared__ int amLast;
  int t = threadIdx.x;
  int row0 = blockIdx.x * 128;
  if (t < 128) sred[t] = 0.f;
  const float* Xt = X + (size_t)row0 * 128;
  #pragma unroll
  for (int c = 0; c < 16; ++c) {
    int f4i = c * 256 + t;
    int row = f4i >> 5, k = (f4i & 31) * 4;
    float4 v = *(const float4*)(Xt + row * 128 + k);
    unsigned int p0 = packbf(v.x, v.y);
    unsigned int p1 = packbf(v.z, v.w);
    *(uint2*)(&As[row * LDA1 + k]) = make_uint2(p0, p1);
  }
  #pragma unroll
  for (int c = 0; c < 32; ++c) {
    int f = c * 256 + t;
    int k = f >> 6, n = f & 63;
    Bs[n * LDA1 + k] = f2bf(W[f]);
  }
  __syncthreads();
  int l = t & 63, wv = t >> 6;
  int lr = l & 15, q = l >> 4;
  int m0 = wv * 32;
  floatx4 acc[2][4];
  #pragma unroll
  for (int mi = 0; mi < 2; ++mi)
    #pragma unroll
    for (int ni = 0; ni < 4; ++ni) acc[mi][ni] = (floatx4)(0.f);
  #pragma unroll
  for (int ks = 0; ks < 128; ks += 32) {
    bf16x8 af[2], bfr[4];
    #pragma unroll
    for (int mi = 0; mi < 2; ++mi)
      af[mi] = *(const bf16x8*)(&As[(m0 + mi * 16 + lr) * LDA1 + ks + q * 8]);
    #pragma unroll
    for (int ni = 0; ni < 4; ++ni)
      bfr[ni] = *(const bf16x8*)(&Bs[(ni * 16 + lr) * LDA1 + ks + q * 8]);
    #pragma unroll
    for (int mi = 0; mi < 2; ++mi)
      #pragma unroll
      for (int ni = 0; ni < 4; ++ni)
        acc[mi][ni] = __builtin_amdgcn_mfma_f32_16x16x32_bf16(af[mi], bfr[ni], acc[mi][ni], 0, 0, 0);
  }
  int b = (row0 >= VN) ? 1 : 0;
  int vbase = row0 - b * VN + m0;
  #pragma unroll
  for (int ni = 0; ni < 4; ++ni) {
    int col = ni * 16 + lr;
    float bv = bias[col];
    size_t sub = (size_t)(b * 2 + (col >> 5)) * VN;
    float s = 0.f, s2 = 0.f;
    #pragma unroll
    for (int mi = 0; mi < 2; ++mi)
      #pragma unroll
      for (int r = 0; r < 4; ++r) {
        float y = acc[mi][ni][r] + bv;
        s += y; s2 += y * y;
        int v = vbase + mi * 16 + q * 4 + r;
        Y[(sub + v) * 32 + (col & 31)] = f2bf(y);
      }
    atomicAdd(&sred[col], s);
    atomicAdd(&sred[64 + col], s2);
  }
  __syncthreads();
  if (t < 128) atomicAdd(&gsum[t], sred[t]);
  __syncthreads();  // drains vmcnt: all gsum atomics complete before counter bump
  if (t == 0) {
    __threadfence();
    amLast = (atomicAdd(counter, 1) == (int)gridDim.x - 1) ? 1 : 0;
  }
  __syncthreads();
  if (amLast && t < 64) {
    float s  = atomicAdd(&gsum[t], 0.f);        // coherent RMW read
    float s2 = atomicAdd(&gsum[64 + t], 0.f);
    float mean = s * (1.f / MROWS);
    float var  = s2 * (1.f / MROWS) - mean * mean;
    float sc = gamma[t] * rsqrtf(var + BN_EPS);
    scshOut[t] = sc;
    scshOut[64 + t] = beta[t] - mean * sc;
  }
}

// ---------------- spmm1: x1 = L relu(bn1(t1))  (BN applied inline) ---------
__global__ __launch_bounds__(256) void spmm1(const unsigned short* __restrict__ T1,
    const int* __restrict__ cols, const float* __restrict__ vals,
    const float* __restrict__ scsh, unsigned short* __restrict__ X1out) {
  int g = blockIdx.x;
  int combo = (g & 7) >> 1;
  int rg = ((g >> 3) << 1) | (g & 1);
  int t = threadIdx.x;
  int wv = t >> 6, lane = t & 63;
  int v = rg * 64 + wv * 16 + (lane >> 2);
  int ch0 = (lane & 3) * 8;
  int cb = (combo & 1) * 32 + ch0;
  float sc[8], sh[8];
  #pragma unroll
  for (int j = 0; j < 8; ++j) { sc[j] = scsh[cb + j]; sh[j] = scsh[64 + cb + j]; }
  const unsigned short* __restrict__ plane = T1 + (size_t)combo * VN * 32;
  float a[8];
  {
    float w0 = vals[v];
    uint4 d = *(const uint4*)(plane + (size_t)v * 32 + ch0);
    float e[8] = {bflo(d.x), bfhi(d.x), bflo(d.y), bfhi(d.y),
                  bflo(d.z), bfhi(d.z), bflo(d.w), bfhi(d.w)};
    #pragma unroll
    for (int j = 0; j < 8; ++j) {
      float h = fmaf(e[j], sc[j], sh[j]);
      h = h > 0.f ? h : 0.f;
      a[j] = w0 * h;
    }
  }
  const int*   __restrict__ cp = cols + VN + v * DEG;
  const float* __restrict__ vp = vals + VN + v * DEG;
  #pragma unroll
  for (int j = 0; j < DEG; ++j) {
    int cj = cp[j];
    float wj = vp[j];
    uint4 d = *(const uint4*)(plane + (size_t)cj * 32 + ch0);
    float e[8] = {bflo(d.x), bfhi(d.x), bflo(d.y), bfhi(d.y),
                  bflo(d.z), bfhi(d.z), bflo(d.w), bfhi(d.w)};
    #pragma unroll
    for (int i = 0; i < 8; ++i) {
      float h = fmaf(e[i], sc[i], sh[i]);
      h = h > 0.f ? h : 0.f;
      a[i] = fmaf(h, wj, a[i]);
    }
  }
  uint4 o;
  o.x = packbf(a[0], a[1]); o.y = packbf(a[2], a[3]);
  o.z = packbf(a[4], a[5]); o.w = packbf(a[6], a[7]);
  *(uint4*)(X1out + (size_t)combo * VN * 32 + (size_t)v * 32 + ch0) = o;
}

// ------------- spmm2: x2 = 2*(L x1) - relu(bn1(t1)) ------------------------
__global__ __launch_bounds__(256) void spmm2(const unsigned short* __restrict__ X1,
    const unsigned short* __restrict__ T1, const int* __restrict__ cols,
    const float* __restrict__ vals, const float* __restrict__ scsh,
    unsigned short* __restrict__ X2out) {
  int g = blockIdx.x;
  int combo = (g & 7) >> 1;
  int rg = ((g >> 3) << 1) | (g & 1);
  int t = threadIdx.x;
  int wv = t >> 6, lane = t & 63;
  int v = rg * 64 + wv * 16 + (lane >> 2);
  int ch0 = (lane & 3) * 8;
  const size_t pbase = (size_t)combo * VN * 32;
  const size_t myoff = pbase + (size_t)v * 32 + ch0;
  const unsigned short* __restrict__ plane = X1 + pbase;
  float a[8];
  {
    float w0 = vals[v];
    uint4 d = *(const uint4*)(X1 + myoff);
    a[0] = w0 * bflo(d.x); a[1] = w0 * bfhi(d.x);
    a[2] = w0 * bflo(d.y); a[3] = w0 * bfhi(d.y);
    a[4] = w0 * bflo(d.z); a[5] = w0 * bfhi(d.z);
    a[6] = w0 * bflo(d.w); a[7] = w0 * bfhi(d.w);
  }
  const int*   __restrict__ cp = cols + VN + v * DEG;
  const float* __restrict__ vp = vals + VN + v * DEG;
  #pragma unroll
  for (int j = 0; j < DEG; ++j) {
    int cj = cp[j];
    float wj = vp[j];
    uint4 d = *(const uint4*)(plane + (size_t)cj * 32 + ch0);
    a[0] = fmaf(bflo(d.x), wj, a[0]); a[1] = fmaf(bfhi(d.x), wj, a[1]);
    a[2] = fmaf(bflo(d.y), wj, a[2]); a[3] = fmaf(bfhi(d.y), wj, a[3]);
    a[4] = fmaf(bflo(d.z), wj, a[4]); a[5] = fmaf(bfhi(d.z), wj, a[5]);
    a[6] = fmaf(bflo(d.w), wj, a[6]); a[7] = fmaf(bfhi(d.w), wj, a[7]);
  }
  int cb = (combo & 1) * 32 + ch0;
  float sc[8], sh[8];
  #pragma unroll
  for (int j = 0; j < 8; ++j) { sc[j] = scsh[cb + j]; sh[j] = scsh[64 + cb + j]; }
  uint4 hr = *(const uint4*)(T1 + myoff);
  float e[8] = {bflo(hr.x), bfhi(hr.x), bflo(hr.y), bfhi(hr.y),
                bflo(hr.z), bfhi(hr.z), bflo(hr.w), bfhi(hr.w)};
  float oo[8];
  #pragma unroll
  for (int j = 0; j < 8; ++j) {
    float h = fmaf(e[j], sc[j], sh[j]);
    h = h > 0.f ? h : 0.f;
    oo[j] = 2.f * a[j] - h;
  }
  uint4 o;
  o.x = packbf(oo[0], oo[1]); o.y = packbf(oo[2], oo[3]);
  o.z = packbf(oo[4], oo[5]); o.w = packbf(oo[6], oo[7]);
  *(uint4*)(X2out + myoff) = o;
}

// ===== GEMM2: t2 = h1@W2[0] + x1@W2[1] + x2@W2[2] + b2 =====================
// h1 term: bn1+relu applied in A-staging (bit-identical to old bn_h1 output).
// Y aliases X0 (t2 overwrites t1): safe, each block rewrites only rows it
// staged, strictly after the barriers. No __restrict__ on X0/Y.
#define LDA2 72
__global__ __launch_bounds__(256) void gemm2(const unsigned short* X0,
    const unsigned short* __restrict__ X1, const unsigned short* __restrict__ X2,
    const float* __restrict__ W, const float* __restrict__ bias,
    const float* __restrict__ scsh, const float* __restrict__ gamma,
    const float* __restrict__ beta, unsigned short* Y,
    float* __restrict__ gsum, int* __restrict__ counter,
    float* __restrict__ scshOut) {
  __shared__ unsigned short As[128 * LDA2];
  __shared__ unsigned short Bs[64 * LDA2];
  __shared__ float sred[128];
  __shared__ int amLast;
  int t = threadIdx.x;
  int row0 = blockIdx.x * 128;
  int b = (row0 >= VN) ? 1 : 0;
  int b2 = b * 2;
  int vb0 = row0 - b * VN;
  if (t < 128) sred[t] = 0.f;
  int kk = (t & 15) * 4;    // k invariant across c8 (256 % 16 == 0)
  int r0 = t >> 4;
  float tsc[4], tsh[4];
  #pragma unroll
  for (int j = 0; j < 4; ++j) { tsc[j] = scsh[kk + j]; tsh[j] = scsh[64 + kk + j]; }
  int l = t & 63, wv = t >> 6;
  int lr = l & 15, q = l >> 4;
  int m0 = wv * 32;
  floatx4 acc[2][4];
  #pragma unroll
  for (int mi = 0; mi < 2; ++mi)
    #pragma unroll
    for (int ni = 0; ni < 4; ++ni) acc[mi][ni] = (floatx4)(0.f);

  #pragma unroll
  for (int term = 0; term < 3; ++term) {
    const unsigned short* Xp = (term == 0) ? X0 : (term == 1) ? X1 : X2;
    const float* Wt = W + term * 64 * 64;
    const unsigned short* srcBase =
        Xp + ((size_t)(b2 + (kk >> 5)) * VN + vb0) * 32 + (kk & 31);
    #pragma unroll
    for (int c8 = 0; c8 < 8; ++c8) {
      int row = c8 * 16 + r0;
      uint2 rawv = *(const uint2*)(srcBase + (size_t)row * 32);
      if (term == 0) {
        float y0 = fmaf(bflo(rawv.x), tsc[0], tsh[0]);
        float y1 = fmaf(bfhi(rawv.x), tsc[1], tsh[1]);
        float y2 = fmaf(bflo(rawv.y), tsc[2], tsh[2]);
        float y3 = fmaf(bfhi(rawv.y), tsc[3], tsh[3]);
        y0 = y0 > 0.f ? y0 : 0.f; y1 = y1 > 0.f ? y1 : 0.f;
        y2 = y2 > 0.f ? y2 : 0.f; y3 = y3 > 0.f ? y3 : 0.f;
        *(uint2*)(&As[row * LDA2 + kk]) = make_uint2(packbf(y0, y1), packbf(y2, y3));
      } else {
        *(uint2*)(&As[row * LDA2 + kk]) = rawv;
      }
    }
    #pragma unroll
    for (int c = 0; c < 16; ++c) {
      int f = c * 256 + t;
      int k = f >> 6, n = f & 63;
      Bs[n * LDA2 + k] = f2bf(Wt[f]);
    }
    __syncthreads();
    #pragma unroll
    for (int ks = 0; ks < 64; ks += 32) {
      bf16x8 af[2], bfr[4];
      #pragma unroll
      for (int mi = 0; mi < 2; ++mi)
        af[mi] = *(const bf16x8*)(&As[(m0 + mi * 16 + lr) * LDA2 + ks + q * 8]);
      #pragma unroll
      for (int ni = 0; ni < 4; ++ni)
        bfr[ni] = *(const bf16x8*)(&Bs[(ni * 16 + lr) * LDA2 + ks + q * 8]);
      #pragma unroll
      for (int mi = 0; mi < 2; ++mi)
        #pragma unroll
        for (int ni = 0; ni < 4; ++ni)
          acc[mi][ni] = __builtin_amdgcn_mfma_f32_16x16x32_bf16(af[mi], bfr[ni], acc[mi][ni], 0, 0, 0);
    }
    __syncthreads();
  }
  int vbase = vb0 + m0;
  #pragma unroll
  for (int ni = 0; ni < 4; ++ni) {
    int col = ni * 16 + lr;
    float bv = bias[col];
    size_t sub = (size_t)(b2 + (col >> 5)) * VN;
    float s = 0.f, s2 = 0.f;
    #pragma unroll
    for (int mi = 0; mi < 2; ++mi)
      #pragma unroll
      for (int r = 0; r < 4; ++r) {
        float y = acc[mi][ni][r] + bv;
        s += y; s2 += y * y;
        int v = vbase + mi * 16 + q * 4 + r;
        Y[(sub + v) * 32 + (col & 31)] = f2bf(y);
      }
    atomicAdd(&sred[col], s);
    atomicAdd(&sred[64 + col], s2);
  }
  __syncthreads();
  if (t < 128) atomicAdd(&gsum[t], sred[t]);
  __syncthreads();
  if (t == 0) {
    __threadfence();
    amLast = (atomicAdd(counter, 1) == (int)gridDim.x - 1) ? 1 : 0;
  }
  __syncthreads();
  if (amLast && t < 64) {
    float s  = atomicAdd(&gsum[t], 0.f);
    float s2 = atomicAdd(&gsum[64 + t], 0.f);
    float mean = s * (1.f / MROWS);
    float var  = s2 * (1.f / MROWS) - mean * mean;
    float sc = gamma[t] * rsqrtf(var + BN_EPS);
    scshOut[t] = sc;
    scshOut[64 + t] = beta[t] - mean * sc;
  }
}

// ====== GEMM3: t3 = relu(bn2(t2)) @ W3 + b3  (full N=128 in one block) =====
__global__ __launch_bounds__(256) void gemm3(const unsigned short* __restrict__ X,
    const float* __restrict__ W, const float* __restrict__ bias,
    const float* __restrict__ scsh, const float* __restrict__ gamma,
    const float* __restrict__ beta, unsigned short* __restrict__ Y,
    float* __restrict__ gsum, int* __restrict__ counter,
    float* __restrict__ scshOut) {
  __shared__ unsigned short As[128 * LDA2];
  __shared__ unsigned short Bs[128 * LDA2];
  __shared__ float sred[256];
  __shared__ int amLast;
  int t = threadIdx.x;
  int row0 = blockIdx.x * 128;
  int b = (row0 >= VN) ? 1 : 0;
  int b2 = b * 2;
  int vb0 = row0 - b * VN;
  sred[t] = 0.f;
  int kk = (t & 15) * 4;
  int r0 = t >> 4;
  float tsc[4], tsh[4];
  #pragma unroll
  for (int j = 0; j < 4; ++j) { tsc[j] = scsh[kk + j]; tsh[j] = scsh[64 + kk + j]; }
  const unsigned short* srcBase =
      X + ((size_t)(b2 + (kk >> 5)) * VN + vb0) * 32 + (kk & 31);
  #pragma unroll
  for (int c8 = 0; c8 < 8; ++c8) {
    int row = c8 * 16 + r0;
    uint2 rawv = *(const uint2*)(srcBase + (size_t)row * 32);
    float y0 = fmaf(bflo(rawv.x), tsc[0], tsh[0]);
    float y1 = fmaf(bfhi(rawv.x), tsc[1], tsh[1]);
    float y2 = fmaf(bflo(rawv.y), tsc[2], tsh[2]);
    float y3 = fmaf(bfhi(rawv.y), tsc[3], tsh[3]);
    y0 = y0 > 0.f ? y0 : 0.f; y1 = y1 > 0.f ? y1 : 0.f;
    y2 = y2 > 0.f ? y2 : 0.f; y3 = y3 > 0.f ? y3 : 0.f;
    *(uint2*)(&As[row * LDA2 + kk]) = make_uint2(packbf(y0, y1), packbf(y2, y3));
  }
  #pragma unroll
  for (int c = 0; c < 32; ++c) {
    int f = c * 256 + t;          // 0..8191
    int k = f >> 7, n = f & 127;
    Bs[n * LDA2 + k] = f2bf(W[k * 128 + n]);
  }
  __syncthreads();
  int l = t & 63, wv = t >> 6;
  int lr = l & 15, q = l >> 4;
  int m0 = wv * 32;
  floatx4 acc[2][8];
  #pragma unroll
  for (int mi = 0; mi < 2; ++mi)
    #pragma unroll
    for (int ni = 0; ni < 8; ++ni) acc[mi][ni] = (floatx4)(0.f);
  #pragma unroll
  for (int ks = 0; ks < 64; ks += 32) {
    bf16x8 af[2], bfr[8];
    #pragma unroll
    for (int mi = 0; mi < 2; ++mi)
      af[mi] = *(const bf16x8*)(&As[(m0 + mi * 16 + lr) * LDA2 + ks + q * 8]);
    #pragma unroll
    for (int ni = 0; ni < 8; ++ni)
      bfr[ni] = *(const bf16x8*)(&Bs[(ni * 16 + lr) * LDA2 + ks + q * 8]);
    #pragma unroll
    for (int mi = 0; mi < 2; ++mi)
      #pragma unroll
      for (int ni = 0; ni < 8; ++ni)
        acc[mi][ni] = __builtin_amdgcn_mfma_f32_16x16x32_bf16(af[mi], bfr[ni], acc[mi][ni], 0, 0, 0);
  }
  #pragma unroll
  for (int ni = 0; ni < 8; ++ni) {
    int col = ni * 16 + lr;
    float bv = bias[col];
    float s = 0.f, s2 = 0.f;
    #pragma unroll
    for (int mi = 0; mi < 2; ++mi)
      #pragma unroll
      for (int r = 0; r < 4; ++r) {
        float y = acc[mi][ni][r] + bv;
        s += y; s2 += y * y;
        int row = row0 + m0 + mi * 16 + q * 4 + r;
        Y[(size_t)row * 128 + col] = f2bf(y);
      }
    atomicAdd(&sred[col], s);
    atomicAdd(&sred[128 + col], s2);
  }
  __syncthreads();
  atomicAdd(&gsum[t], sred[t]);   // all 256 threads
  __syncthreads();
  if (t == 0) {
    __threadfence();
    amLast = (atomicAdd(counter, 1) == (int)gridDim.x - 1) ? 1 : 0;
  }
  __syncthreads();
  if (amLast && t < 128) {
    float s  = atomicAdd(&gsum[t], 0.f);
    float s2 = atomicAdd(&gsum[128 + t], 0.f);
    float mean = s * (1.f / MROWS);
    float var  = s2 * (1.f / MROWS) - mean * mean;
    float sc = gamma[t] * rsqrtf(var + BN_EPS);
    scshOut[t] = sc;
    scshOut[128 + t] = beta[t] - mean * sc;
  }
}

// ---------------- final BN apply + ReLU, bf16 -> fp32 ----------------------
__global__ __launch_bounds__(256) void bn_apply_final(const unsigned short* __restrict__ T,
    float* __restrict__ Y, const float* __restrict__ scsh) {
  size_t i4 = ((size_t)blockIdx.x * 256 + threadIdx.x) * 4;
  int c0 = (int)(i4 & 127);
  ushort4 tv = *(const ushort4*)(T + i4);
  unsigned short sv[4] = {tv.x, tv.y, tv.z, tv.w};
  float ov[4];
  #pragma unroll
  for (int j = 0; j < 4; ++j) {
    int c = c0 + j;
    float y = fmaf(bf2f(sv[j]), scsh[c], scsh[128 + c]);
    ov[j] = y > 0.f ? y : 0.f;
  }
  *(float4*)(Y + i4) = make_float4(ov[0], ov[1], ov[2], ov[3]);
}

extern "C" void kernel_launch(void* const* d_in, const int* in_sizes, int n_in,
                              void* d_out, int out_size, void* d_ws, size_t ws_size,
                              hipStream_t stream) {
  const float* x    = (const float*)d_in[0];
  const int*   cols = (const int*)  d_in[2];
  const float* vals = (const float*)d_in[3];
  const float* W1   = (const float*)d_in[4];
  const float* b1   = (const float*)d_in[5];
  const float* g1   = (const float*)d_in[6];
  const float* be1  = (const float*)d_in[7];
  const float* W2   = (const float*)d_in[8];
  const float* b2   = (const float*)d_in[9];
  const float* g2   = (const float*)d_in[10];
  const float* be2  = (const float*)d_in[11];
  const float* W3   = (const float*)d_in[12];
  const float* b3   = (const float*)d_in[13];
  const float* g3   = (const float*)d_in[14];
  const float* be3  = (const float*)d_in[15];
  float* out = (float*)d_out;

  const size_t PL = (size_t)MROWS * 64;          // plane elements
  unsigned short* P0 = (unsigned short*)d_ws;    // t1, then t2
  unsigned short* P1 = P0 + PL;                  // x1
  unsigned short* P2 = P1 + PL;                  // x2, then t3 [MROWS,128]
  float* ctrl  = (float*)(P2 + 2 * PL);
  float* gsum1 = ctrl;                           // 128
  float* gsum2 = ctrl + 128;                     // 128
  float* gsum3 = ctrl + 256;                     // 256
  int*   cnts  = (int*)(ctrl + 512);             // 3 counters (pad to 4)
  float* scsh1 = ctrl + 516;                     // 128
  float* scsh2 = scsh1 + 128;                    // 128
  float* scsh3 = scsh2 + 128;                    // 256

  // zero accumulators + counters (ws is re-poisoned by the harness each iter)
  hipMemsetAsync(ctrl, 0, 516 * sizeof(float), stream);

  dim3 blk(256);
  int rowb = MROWS / 128;                        // 768
  int spmm_blocks = 3072;                        // 64 rows x 4 combos
  int ap128_blocks = (int)(PL * 2 / 4 / 256);    // 12288

  // Layer 1: gemm + in-kernel BN-stat finalization
  gemm1<<<rowb, blk, 0, stream>>>(x, W1, b1, g1, be1, P0, gsum1, cnts + 0, scsh1);

  // Layer 2 (K=3 Chebyshev); h1 = relu(bn1(t1)) applied inline everywhere
  spmm1<<<spmm_blocks, blk, 0, stream>>>(P0, cols, vals, scsh1, P1);
  spmm2<<<spmm_blocks, blk, 0, stream>>>(P1, P0, cols, vals, scsh1, P2);
  gemm2<<<rowb, blk, 0, stream>>>(P0, P1, P2, W2, b2, scsh1, g2, be2, P0, gsum2, cnts + 1, scsh2);

  // Layer 3; bn2-apply fused into gemm3 A-staging; full N=128 per block
  gemm3<<<rowb, blk, 0, stream>>>(P0, W3, b3, scsh2, g3, be3, P2, gsum3, cnts + 2, scsh3);
  bn_apply_final<<<ap128_blocks, blk, 0, stream>>>(P2, out, scsh3);
}

// Round 2
// 290.951 us; speedup vs baseline: 1.1594x; 1.1594x over previous
//
#include <hip/hip_runtime.h>

#define VN 49152
#define DEG 20
#define NB 2
#define MROWS (NB * VN)   // 98304 rows

static constexpr float BN_EPS = 1e-5f;

typedef short bf16x8 __attribute__((ext_vector_type(8)));
typedef float floatx4 __attribute__((ext_vector_type(4)));

__device__ __forceinline__ unsigned short f2bf(float f) {
  unsigned int u = __builtin_bit_cast(unsigned int, f);
  u += 0x7FFFu + ((u >> 16) & 1u);            // RNE
  return (unsigned short)(u >> 16);
}
__device__ __forceinline__ float bf2f(unsigned short h) {
  unsigned int u = ((unsigned int)h) << 16;
  return __builtin_bit_cast(float, u);
}
// packed-bf16 tricks: 1 VALU per element
__device__ __forceinline__ float bflo(unsigned int u) {
  return __builtin_bit_cast(float, u << 16);
}
__device__ __forceinline__ float bfhi(unsigned int u) {
  return __builtin_bit_cast(float, u & 0xFFFF0000u);
}
__device__ __forceinline__ unsigned int packbf(float a, float b) {
  return (unsigned int)f2bf(a) | ((unsigned int)f2bf(b) << 16);
}

// Per-channel BN scale/shift recomputed by CONSUMERS from gsum partials.
// gsum layout: [0..S-1] = channel sums, [S..2S-1] = channel sumsq.
// No fence/counter in producers: kernel-boundary visibility is enough.
__device__ __forceinline__ void scsh_from(const float* __restrict__ gsum,
    const float* __restrict__ gamma, const float* __restrict__ beta,
    int c, int S, float& sc, float& sh) {
  float mean = gsum[c] * (1.f / MROWS);
  float var  = gsum[S + c] * (1.f / MROWS) - mean * mean;
  sc = gamma[c] * rsqrtf(var + BN_EPS);
  sh = beta[c] - mean * sc;
}

// Feature planes (64-ch) are stored SWIZZLED as 4 sub-planes
// [batch][chalf][VN][32]: addr(b,v,ch) = ((b*2 + ch/32)*VN + v)*32 + ch%32.
// A (batch,chalf) combo = contiguous 3.15 MB -> fits one XCD L2.
// spmm blocks pin combo via blockIdx%8 so each combo lives on 2 XCDs.

// ======================= GEMM1: t1 = x @ W1 + b1 ===========================
#define LDA1 136
__global__ __launch_bounds__(256) void gemm1(const float* __restrict__ X,
    const float* __restrict__ W, const float* __restrict__ bias,
    unsigned short* __restrict__ Y, float* __restrict__ gsum) {
  __shared__ unsigned short As[128 * LDA1];
  __shared__ unsigned short Bs[64 * LDA1];
  __shared__ float sred[128];
  int t = threadIdx.x;
  int row0 = blockIdx.x * 128;
  if (t < 128) sred[t] = 0.f;
  const float* Xt = X + (size_t)row0 * 128;
  #pragma unroll
  for (int c = 0; c < 16; ++c) {
    int f4i = c * 256 + t;
    int row = f4i >> 5, k = (f4i & 31) * 4;
    float4 v = *(const float4*)(Xt + row * 128 + k);
    unsigned int p0 = packbf(v.x, v.y);
    unsigned int p1 = packbf(v.z, v.w);
    *(uint2*)(&As[row * LDA1 + k]) = make_uint2(p0, p1);
  }
  #pragma unroll
  for (int c = 0; c < 32; ++c) {
    int f = c * 256 + t;
    int k = f >> 6, n = f & 63;
    Bs[n * LDA1 + k] = f2bf(W[f]);
  }
  __syncthreads();
  int l = t & 63, wv = t >> 6;
  int lr = l & 15, q = l >> 4;
  int m0 = wv * 32;
  floatx4 acc[2][4];
  #pragma unroll
  for (int mi = 0; mi < 2; ++mi)
    #pragma unroll
    for (int ni = 0; ni < 4; ++ni) acc[mi][ni] = (floatx4)(0.f);
  #pragma unroll
  for (int ks = 0; ks < 128; ks += 32) {
    bf16x8 af[2], bfr[4];
    #pragma unroll
    for (int mi = 0; mi < 2; ++mi)
      af[mi] = *(const bf16x8*)(&As[(m0 + mi * 16 + lr) * LDA1 + ks + q * 8]);
    #pragma unroll
    for (int ni = 0; ni < 4; ++ni)
      bfr[ni] = *(const bf16x8*)(&Bs[(ni * 16 + lr) * LDA1 + ks + q * 8]);
    #pragma unroll
    for (int mi = 0; mi < 2; ++mi)
      #pragma unroll
      for (int ni = 0; ni < 4; ++ni)
        acc[mi][ni] = __builtin_amdgcn_mfma_f32_16x16x32_bf16(af[mi], bfr[ni], acc[mi][ni], 0, 0, 0);
  }
  int b = (row0 >= VN) ? 1 : 0;
  int vbase = row0 - b * VN + m0;
  #pragma unroll
  for (int ni = 0; ni < 4; ++ni) {
    int col = ni * 16 + lr;
    float bv = bias[col];
    size_t sub = (size_t)(b * 2 + (col >> 5)) * VN;
    float s = 0.f, s2 = 0.f;
    #pragma unroll
    for (int mi = 0; mi < 2; ++mi)
      #pragma unroll
      for (int r = 0; r < 4; ++r) {
        float y = acc[mi][ni][r] + bv;
        s += y; s2 += y * y;
        int v = vbase + mi * 16 + q * 4 + r;
        Y[(sub + v) * 32 + (col & 31)] = f2bf(y);
      }
    atomicAdd(&sred[col], s);
    atomicAdd(&sred[64 + col], s2);
  }
  __syncthreads();
  if (t < 128) atomicAdd(&gsum[t], sred[t]);
}

// ---------------- spmm1: x1 = L relu(bn1(t1))  (BN applied inline) ---------
__global__ __launch_bounds__(256) void spmm1(const unsigned short* __restrict__ T1,
    const int* __restrict__ cols, const float* __restrict__ vals,
    const float* __restrict__ gsum, const float* __restrict__ gamma,
    const float* __restrict__ beta, unsigned short* __restrict__ X1out) {
  int g = blockIdx.x;
  int combo = (g & 7) >> 1;
  int rg = ((g >> 3) << 1) | (g & 1);
  int t = threadIdx.x;
  int wv = t >> 6, lane = t & 63;
  int v = rg * 64 + wv * 16 + (lane >> 2);
  int ch0 = (lane & 3) * 8;
  int cb = (combo & 1) * 32 + ch0;
  float sc[8], sh[8];
  #pragma unroll
  for (int j = 0; j < 8; ++j) scsh_from(gsum, gamma, beta, cb + j, 64, sc[j], sh[j]);
  const unsigned short* __restrict__ plane = T1 + (size_t)combo * VN * 32;
  float a[8];
  {
    float w0 = vals[v];
    uint4 d = *(const uint4*)(plane + (size_t)v * 32 + ch0);
    float e[8] = {bflo(d.x), bfhi(d.x), bflo(d.y), bfhi(d.y),
                  bflo(d.z), bfhi(d.z), bflo(d.w), bfhi(d.w)};
    #pragma unroll
    for (int j = 0; j < 8; ++j) {
      float h = fmaf(e[j], sc[j], sh[j]);
      h = h > 0.f ? h : 0.f;
      a[j] = w0 * h;
    }
  }
  const int*   __restrict__ cp = cols + VN + v * DEG;
  const float* __restrict__ vp = vals + VN + v * DEG;
  #pragma unroll
  for (int j = 0; j < DEG; ++j) {
    int cj = cp[j];
    float wj = vp[j];
    uint4 d = *(const uint4*)(plane + (size_t)cj * 32 + ch0);
    float e[8] = {bflo(d.x), bfhi(d.x), bflo(d.y), bfhi(d.y),
                  bflo(d.z), bfhi(d.z), bflo(d.w), bfhi(d.w)};
    #pragma unroll
    for (int i = 0; i < 8; ++i) {
      float h = fmaf(e[i], sc[i], sh[i]);
      h = h > 0.f ? h : 0.f;
      a[i] = fmaf(h, wj, a[i]);
    }
  }
  uint4 o;
  o.x = packbf(a[0], a[1]); o.y = packbf(a[2], a[3]);
  o.z = packbf(a[4], a[5]); o.w = packbf(a[6], a[7]);
  *(uint4*)(X1out + (size_t)combo * VN * 32 + (size_t)v * 32 + ch0) = o;
}

// ------------- spmm2: x2 = 2*(L x1) - relu(bn1(t1)) ------------------------
__global__ __launch_bounds__(256) void spmm2(const unsigned short* __restrict__ X1,
    const unsigned short* __restrict__ T1, const int* __restrict__ cols,
    const float* __restrict__ vals, const float* __restrict__ gsum,
    const float* __restrict__ gamma, const float* __restrict__ beta,
    unsigned short* __restrict__ X2out) {
  int g = blockIdx.x;
  int combo = (g & 7) >> 1;
  int rg = ((g >> 3) << 1) | (g & 1);
  int t = threadIdx.x;
  int wv = t >> 6, lane = t & 63;
  int v = rg * 64 + wv * 16 + (lane >> 2);
  int ch0 = (lane & 3) * 8;
  const size_t pbase = (size_t)combo * VN * 32;
  const size_t myoff = pbase + (size_t)v * 32 + ch0;
  const unsigned short* __restrict__ plane = X1 + pbase;
  float a[8];
  {
    float w0 = vals[v];
    uint4 d = *(const uint4*)(X1 + myoff);
    a[0] = w0 * bflo(d.x); a[1] = w0 * bfhi(d.x);
    a[2] = w0 * bflo(d.y); a[3] = w0 * bfhi(d.y);
    a[4] = w0 * bflo(d.z); a[5] = w0 * bfhi(d.z);
    a[6] = w0 * bflo(d.w); a[7] = w0 * bfhi(d.w);
  }
  const int*   __restrict__ cp = cols + VN + v * DEG;
  const float* __restrict__ vp = vals + VN + v * DEG;
  #pragma unroll
  for (int j = 0; j < DEG; ++j) {
    int cj = cp[j];
    float wj = vp[j];
    uint4 d = *(const uint4*)(plane + (size_t)cj * 32 + ch0);
    a[0] = fmaf(bflo(d.x), wj, a[0]); a[1] = fmaf(bfhi(d.x), wj, a[1]);
    a[2] = fmaf(bflo(d.y), wj, a[2]); a[3] = fmaf(bfhi(d.y), wj, a[3]);
    a[4] = fmaf(bflo(d.z), wj, a[4]); a[5] = fmaf(bfhi(d.z), wj, a[5]);
    a[6] = fmaf(bflo(d.w), wj, a[6]); a[7] = fmaf(bfhi(d.w), wj, a[7]);
  }
  int cb = (combo & 1) * 32 + ch0;
  float sc[8], sh[8];
  #pragma unroll
  for (int j = 0; j < 8; ++j) scsh_from(gsum, gamma, beta, cb + j, 64, sc[j], sh[j]);
  uint4 hr = *(const uint4*)(T1 + myoff);
  float e[8] = {bflo(hr.x), bfhi(hr.x), bflo(hr.y), bfhi(hr.y),
                bflo(hr.z), bfhi(hr.z), bflo(hr.w), bfhi(hr.w)};
  float oo[8];
  #pragma unroll
  for (int j = 0; j < 8; ++j) {
    float h = fmaf(e[j], sc[j], sh[j]);
    h = h > 0.f ? h : 0.f;
    oo[j] = 2.f * a[j] - h;
  }
  uint4 o;
  o.x = packbf(oo[0], oo[1]); o.y = packbf(oo[2], oo[3]);
  o.z = packbf(oo[4], oo[5]); o.w = packbf(oo[6], oo[7]);
  *(uint4*)(X2out + myoff) = o;
}

// ===== GEMM2: t2 = h1@W2[0] + x1@W2[1] + x2@W2[2] + b2 =====================
// h1 term: bn1+relu applied in A-staging. Y aliases X0 (t2 overwrites t1):
// safe, each block rewrites only the rows it staged, after the barriers.
#define LDA2 72
__global__ __launch_bounds__(256) void gemm2(const unsigned short* X0,
    const unsigned short* __restrict__ X1, const unsigned short* __restrict__ X2,
    const float* __restrict__ W, const float* __restrict__ bias,
    const float* __restrict__ gsumIn, const float* __restrict__ gamma,
    const float* __restrict__ beta, unsigned short* Y,
    float* __restrict__ gsumOut) {
  __shared__ unsigned short As[128 * LDA2];
  __shared__ unsigned short Bs[64 * LDA2];
  __shared__ float sred[128];
  int t = threadIdx.x;
  int row0 = blockIdx.x * 128;
  int b = (row0 >= VN) ? 1 : 0;
  int b2 = b * 2;
  int vb0 = row0 - b * VN;
  if (t < 128) sred[t] = 0.f;
  int kk = (t & 15) * 4;    // k invariant across c8 (256 % 16 == 0)
  int r0 = t >> 4;
  float tsc[4], tsh[4];
  #pragma unroll
  for (int j = 0; j < 4; ++j) scsh_from(gsumIn, gamma, beta, kk + j, 64, tsc[j], tsh[j]);
  int l = t & 63, wv = t >> 6;
  int lr = l & 15, q = l >> 4;
  int m0 = wv * 32;
  floatx4 acc[2][4];
  #pragma unroll
  for (int mi = 0; mi < 2; ++mi)
    #pragma unroll
    for (int ni = 0; ni < 4; ++ni) acc[mi][ni] = (floatx4)(0.f);

  #pragma unroll
  for (int term = 0; term < 3; ++term) {
    const unsigned short* Xp = (term == 0) ? X0 : (term == 1) ? X1 : X2;
    const float* Wt = W + term * 64 * 64;
    const unsigned short* srcBase =
        Xp + ((size_t)(b2 + (kk >> 5)) * VN + vb0) * 32 + (kk & 31);
    #pragma unroll
    for (int c8 = 0; c8 < 8; ++c8) {
      int row = c8 * 16 + r0;
      uint2 rawv = *(const uint2*)(srcBase + (size_t)row * 32);
      if (term == 0) {
        float y0 = fmaf(bflo(rawv.x), tsc[0], tsh[0]);
        float y1 = fmaf(bfhi(rawv.x), tsc[1], tsh[1]);
        float y2 = fmaf(bflo(rawv.y), tsc[2], tsh[2]);
        float y3 = fmaf(bfhi(rawv.y), tsc[3], tsh[3]);
        y0 = y0 > 0.f ? y0 : 0.f; y1 = y1 > 0.f ? y1 : 0.f;
        y2 = y2 > 0.f ? y2 : 0.f; y3 = y3 > 0.f ? y3 : 0.f;
        *(uint2*)(&As[row * LDA2 + kk]) = make_uint2(packbf(y0, y1), packbf(y2, y3));
      } else {
        *(uint2*)(&As[row * LDA2 + kk]) = rawv;
      }
    }
    #pragma unroll
    for (int c = 0; c < 16; ++c) {
      int f = c * 256 + t;
      int k = f >> 6, n = f & 63;
      Bs[n * LDA2 + k] = f2bf(Wt[f]);
    }
    __syncthreads();
    #pragma unroll
    for (int ks = 0; ks < 64; ks += 32) {
      bf16x8 af[2], bfr[4];
      #pragma unroll
      for (int mi = 0; mi < 2; ++mi)
        af[mi] = *(const bf16x8*)(&As[(m0 + mi * 16 + lr) * LDA2 + ks + q * 8]);
      #pragma unroll
      for (int ni = 0; ni < 4; ++ni)
        bfr[ni] = *(const bf16x8*)(&Bs[(ni * 16 + lr) * LDA2 + ks + q * 8]);
      #pragma unroll
      for (int mi = 0; mi < 2; ++mi)
        #pragma unroll
        for (int ni = 0; ni < 4; ++ni)
          acc[mi][ni] = __builtin_amdgcn_mfma_f32_16x16x32_bf16(af[mi], bfr[ni], acc[mi][ni], 0, 0, 0);
    }
    __syncthreads();
  }
  int vbase = vb0 + m0;
  #pragma unroll
  for (int ni = 0; ni < 4; ++ni) {
    int col = ni * 16 + lr;
    float bv = bias[col];
    size_t sub = (size_t)(b2 + (col >> 5)) * VN;
    float s = 0.f, s2 = 0.f;
    #pragma unroll
    for (int mi = 0; mi < 2; ++mi)
      #pragma unroll
      for (int r = 0; r < 4; ++r) {
        float y = acc[mi][ni][r] + bv;
        s += y; s2 += y * y;
        int v = vbase + mi * 16 + q * 4 + r;
        Y[(sub + v) * 32 + (col & 31)] = f2bf(y);
      }
    atomicAdd(&sred[col], s);
    atomicAdd(&sred[64 + col], s2);
  }
  __syncthreads();
  if (t < 128) atomicAdd(&gsumOut[t], sred[t]);
}

// ====== GEMM3: t3 = relu(bn2(t2)) @ W3 + b3  (two 64-col halves, y-grid) ===
__global__ __launch_bounds__(256) void gemm3(const unsigned short* __restrict__ X,
    const float* __restrict__ W, const float* __restrict__ bias,
    const float* __restrict__ gsumIn, const float* __restrict__ gamma,
    const float* __restrict__ beta, unsigned short* __restrict__ Y,
    float* __restrict__ gsumOut) {
  __shared__ unsigned short As[128 * LDA2];
  __shared__ unsigned short Bs[64 * LDA2];
  __shared__ float sred[128];
  int t = threadIdx.x;
  int row0 = blockIdx.x * 128;
  int n0 = blockIdx.y * 64;
  int b = (row0 >= VN) ? 1 : 0;
  int b2 = b * 2;
  int vb0 = row0 - b * VN;
  if (t < 128) sred[t] = 0.f;
  int kk = (t & 15) * 4;
  int r0 = t >> 4;
  float tsc[4], tsh[4];
  #pragma unroll
  for (int j = 0; j < 4; ++j) scsh_from(gsumIn, gamma, beta, kk + j, 64, tsc[j], tsh[j]);
  const unsigned short* srcBase =
      X + ((size_t)(b2 + (kk >> 5)) * VN + vb0) * 32 + (kk & 31);
  #pragma unroll
  for (int c8 = 0; c8 < 8; ++c8) {
    int row = c8 * 16 + r0;
    uint2 rawv = *(const uint2*)(srcBase + (size_t)row * 32);
    float y0 = fmaf(bflo(rawv.x), tsc[0], tsh[0]);
    float y1 = fmaf(bfhi(rawv.x), tsc[1], tsh[1]);
    float y2 = fmaf(bflo(rawv.y), tsc[2], tsh[2]);
    float y3 = fmaf(bfhi(rawv.y), tsc[3], tsh[3]);
    y0 = y0 > 0.f ? y0 : 0.f; y1 = y1 > 0.f ? y1 : 0.f;
    y2 = y2 > 0.f ? y2 : 0.f; y3 = y3 > 0.f ? y3 : 0.f;
    *(uint2*)(&As[row * LDA2 + kk]) = make_uint2(packbf(y0, y1), packbf(y2, y3));
  }
  #pragma unroll
  for (int c = 0; c < 16; ++c) {
    int f = c * 256 + t;
    int k = f >> 6, n = f & 63;
    Bs[n * LDA2 + k] = f2bf(W[k * 128 + n0 + n]);
  }
  __syncthreads();
  int l = t & 63, wv = t >> 6;
  int lr = l & 15, q = l >> 4;
  int m0 = wv * 32;
  floatx4 acc[2][4];
  #pragma unroll
  for (int mi = 0; mi < 2; ++mi)
    #pragma unroll
    for (int ni = 0; ni < 4; ++ni) acc[mi][ni] = (floatx4)(0.f);
  #pragma unroll
  for (int ks = 0; ks < 64; ks += 32) {
    bf16x8 af[2], bfr[4];
    #pragma unroll
    for (int mi = 0; mi < 2; ++mi)
      af[mi] = *(const bf16x8*)(&As[(m0 + mi * 16 + lr) * LDA2 + ks + q * 8]);
    #pragma unroll
    for (int ni = 0; ni < 4; ++ni)
      bfr[ni] = *(const bf16x8*)(&Bs[(ni * 16 + lr) * LDA2 + ks + q * 8]);
    #pragma unroll
    for (int mi = 0; mi < 2; ++mi)
      #pragma unroll
      for (int ni = 0; ni < 4; ++ni)
        acc[mi][ni] = __builtin_amdgcn_mfma_f32_16x16x32_bf16(af[mi], bfr[ni], acc[mi][ni], 0, 0, 0);
  }
  #pragma unroll
  for (int ni = 0; ni < 4; ++ni) {
    int lc = ni * 16 + lr;
    int col = n0 + lc;
    float bv = bias[col];
    float s = 0.f, s2 = 0.f;
    #pragma unroll
    for (int mi = 0; mi < 2; ++mi)
      #pragma unroll
      for (int r = 0; r < 4; ++r) {
        float y = acc[mi][ni][r] + bv;
        s += y; s2 += y * y;
        int row = row0 + m0 + mi * 16 + q * 4 + r;
        Y[(size_t)row * 128 + col] = f2bf(y);
      }
    atomicAdd(&sred[lc], s);
    atomicAdd(&sred[64 + lc], s2);
  }
  __syncthreads();
  // gsumOut: [0..127]=sums, [128..255]=sumsq (128 channels)
  if (t < 128) {
    int lc = t & 63, p = t >> 6;
    atomicAdd(&gsumOut[p * 128 + n0 + lc], sred[t]);
  }
}

// ---------------- final BN apply + ReLU, bf16 -> fp32 ----------------------
__global__ __launch_bounds__(256) void bn_apply_final(const unsigned short* __restrict__ T,
    float* __restrict__ Y, const float* __restrict__ gsum,
    const float* __restrict__ gamma, const float* __restrict__ beta) {
  size_t i4 = ((size_t)blockIdx.x * 256 + threadIdx.x) * 4;
  int c0 = (int)(i4 & 127);
  ushort4 tv = *(const ushort4*)(T + i4);
  unsigned short sv[4] = {tv.x, tv.y, tv.z, tv.w};
  float ov[4];
  #pragma unroll
  for (int j = 0; j < 4; ++j) {
    int c = c0 + j;
    float sc, sh;
    scsh_from(gsum, gamma, beta, c, 128, sc, sh);
    float y = fmaf(bf2f(sv[j]), sc, sh);
    ov[j] = y > 0.f ? y : 0.f;
  }
  *(float4*)(Y + i4) = make_float4(ov[0], ov[1], ov[2], ov[3]);
}

extern "C" void kernel_launch(void* const* d_in, const int* in_sizes, int n_in,
                              void* d_out, int out_size, void* d_ws, size_t ws_size,
                              hipStream_t stream) {
  const float* x    = (const float*)d_in[0];
  const int*   cols = (const int*)  d_in[2];
  const float* vals = (const float*)d_in[3];
  const float* W1   = (const float*)d_in[4];
  const float* b1   = (const float*)d_in[5];
  const float* g1   = (const float*)d_in[6];
  const float* be1  = (const float*)d_in[7];
  const float* W2   = (const float*)d_in[8];
  const float* b2   = (const float*)d_in[9];
  const float* g2   = (const float*)d_in[10];
  const float* be2  = (const float*)d_in[11];
  const float* W3   = (const float*)d_in[12];
  const float* b3   = (const float*)d_in[13];
  const float* g3   = (const float*)d_in[14];
  const float* be3  = (const float*)d_in[15];
  float* out = (float*)d_out;

  const size_t PL = (size_t)MROWS * 64;          // plane elements
  unsigned short* P0 = (unsigned short*)d_ws;    // t1, then t2
  unsigned short* P1 = P0 + PL;                  // x1
  unsigned short* P2 = P1 + PL;                  // x2, then t3 [MROWS,128]
  float* ctrl  = (float*)(P2 + 2 * PL);
  float* gsum1 = ctrl;                           // 128 (64 sum + 64 sumsq)
  float* gsum2 = ctrl + 128;                     // 128
  float* gsum3 = ctrl + 256;                     // 256 (128 sum + 128 sumsq)

  // zero stat accumulators (ws is re-poisoned by the harness each iter)
  hipMemsetAsync(ctrl, 0, 512 * sizeof(float), stream);

  dim3 blk(256);
  int rowb = MROWS / 128;                        // 768
  int spmm_blocks = 3072;                        // 64 rows x 4 combos
  int ap128_blocks = (int)(PL * 2 / 4 / 256);    // 12288

  // Layer 1
  gemm1<<<rowb, blk, 0, stream>>>(x, W1, b1, P0, gsum1);

  // Layer 2 (K=3 Chebyshev); h1 = relu(bn1(t1)) applied inline everywhere
  spmm1<<<spmm_blocks, blk, 0, stream>>>(P0, cols, vals, gsum1, g1, be1, P1);
  spmm2<<<spmm_blocks, blk, 0, stream>>>(P1, P0, cols, vals, gsum1, g1, be1, P2);
  gemm2<<<rowb, blk, 0, stream>>>(P0, P1, P2, W2, b2, gsum1, g1, be1, P0, gsum2);

  // Layer 3; bn2-apply fused into gemm3 A-staging; two 64-col halves
  dim3 g3grid(rowb, 2);
  gemm3<<<g3grid, blk, 0, stream>>>(P0, W3, b3, gsum2, g2, be2, P2, gsum3);
  bn_apply_final<<<ap128_blocks, blk, 0, stream>>>(P2, out, gsum3, g3, be3);
}